// Round 1
// baseline (801.313 us; speedup 1.0000x reference)
//
#include <hip/hip_runtime.h>

// Problem constants (fixed by reference)
#define NATOMS 200000
#define NEDGE  800000
#define NBOND  400000   // NEDGE/2
#define HDIM   512
#define AF     133
#define BFEAT  14
#define NGRAPH 4096

// d_out layout: node_pred [NATOMS*AF] | edge_pred [NBOND*BFEAT] | graph_pred [NGRAPH]
#define NODE_OUT_SZ (NATOMS * AF)          // 26,600,000
#define EDGE_OUT_SZ (NBOND * BFEAT)        //  5,600,000

// ws layout (bytes)
#define WS_P     0                          // float  [NATOMS][16]  (cols 0..13 used)  12,800,000 B
#define WS_BMAT  12800000                   // f16    [160][512]    163,840 B  (n-major, transposed)
#define WS_BIAS  12963840                   // float  [160]         640 B
#define WS_GEF   12964480                   // float  [4096][512]   8,388,608 B (pooled emb, fp32, atomics)
#define WS_WG1T  21353088                   // f16    [512][512]    524,288 B (n-major)

typedef _Float16 half8 __attribute__((ext_vector_type(8)));
typedef float floatx4 __attribute__((ext_vector_type(4)));

// ---------------------------------------------------------------------------
// Pack: combined B matrix [W_node | W_edge] transposed to n-major f16, bias,
// W_g1 transposed f16, graph_pred init to b_g2.
// ---------------------------------------------------------------------------
__global__ void pack_kernel(const float* __restrict__ Wn, const float* __restrict__ bn,
                            const float* __restrict__ We, const float* __restrict__ be,
                            const float* __restrict__ Wg1, const float* __restrict__ bg2,
                            _Float16* __restrict__ Bmat, float* __restrict__ bias,
                            _Float16* __restrict__ Wg1t, float* __restrict__ gpred) {
    int idx = blockIdx.x * 256 + threadIdx.x;
    if (idx < 160 * 512) {                      // Bmat[n][k] = W[k][n]
        int n = idx >> 9, k = idx & 511;
        float v = 0.f;
        if (n < AF)              v = Wn[k * AF + n];
        else if (n < AF + BFEAT) v = We[k * BFEAT + (n - AF)];
        Bmat[idx] = (_Float16)v;
    } else if (idx < 160 * 512 + 512 * 512) {   // Wg1t[n][k] = Wg1[k][n]
        int i = idx - 160 * 512;
        int n = i >> 9, k = i & 511;
        Wg1t[i] = (_Float16)Wg1[k * HDIM + n];
    } else if (idx < 160 * 512 + 512 * 512 + 160) {
        int n = idx - (160 * 512 + 512 * 512);
        float v = 0.f;
        if (n < AF)              v = bn[n];
        else if (n < AF + BFEAT) v = be[n - AF];
        bias[n] = v;
    } else if (idx < 160 * 512 + 512 * 512 + 160 + NGRAPH) {
        gpred[idx - (160 * 512 + 512 * 512 + 160)] = bg2[0];
    }
}

// Zero the fp32 graph-embedding accumulator (ws is poisoned 0xAA).
__global__ void zero_ge(float4* __restrict__ GEf4) {
    GEf4[blockIdx.x * 256 + threadIdx.x] = make_float4(0.f, 0.f, 0.f, 0.f);
}

// ---------------------------------------------------------------------------
// GEMM1: C[N x 160] = A(f32->f16)[N x 512] @ Bmat^T, cols 0..132 -> node_pred,
// cols 133..146 -> P (stride 16). BM=128 BN=160 BK=64, 4 waves (2x2), wave
// tile 64x80 = 4x5 MFMA 16x16x32 f16 tiles.
//
// v2 structure (latency-bound fix):
//  - B fragments load straight from global (Bmat is 160 KB, L2-resident);
//    no Bs LDS staging.
//  - As double-buffered (2x128x72 f16 = 36.9 KB), ONE barrier per ko.
//  - Next A tile prefetched into regs, issued AFTER this ko's B-frag loads
//    (so vmcnt waits for B don't drain the prefetch) and BEFORE the MFMAs;
//    consumed (cvt f32->f16 + LDS write to the other buffer) after pooling.
//  - Pooling LDS reads batched 8-wide, segment logic on registers.
// FUSED POOLING: wave w sums rows w*32..w*32+31 of the resident tile for its
// 64 columns, segmented by graph id (wave-uniform branch), one coalesced
// 256B fp32 atomicAdd burst per graph boundary into GEf.
// ---------------------------------------------------------------------------
__global__ __launch_bounds__(256, 3) void gemm_node(const float* __restrict__ A,
                                                    const _Float16* __restrict__ Bm,
                                                    const float* __restrict__ bias,
                                                    const int* __restrict__ batch,
                                                    float* __restrict__ node_out,
                                                    float* __restrict__ P,
                                                    float* __restrict__ GEf) {
    __shared__ _Float16 As[2][128][72];   // +8 pad per row
    __shared__ int bg[128];

    const int t    = threadIdx.x;
    const int bm   = blockIdx.x;
    const int w    = t >> 6, l = t & 63, quad = l >> 4, lr = l & 15;
    const int wm   = w & 1, wn = w >> 1;

    if (t < 128) {
        int grow = bm * 128 + t;
        bg[t] = (grow < NATOMS) ? batch[grow] : -1;
    }

    floatx4 acc[4][5];
#pragma unroll
    for (int mt = 0; mt < 4; ++mt)
#pragma unroll
        for (int nt = 0; nt < 5; ++nt)
            acc[mt][nt] = (floatx4){0.f, 0.f, 0.f, 0.f};

    const int arow0 = t >> 2;          // 0..63
    const int aseg  = (t & 3) * 16;    // 0,16,32,48 (floats)
    const int pc    = t & 63;          // pooling column within the ko tile
    const int pq    = w;               // pooling row-quarter = wave id

    // B fragment element-offsets (32-bit voffset vs uniform Bm base)
    int boff[5];
#pragma unroll
    for (int nt = 0; nt < 5; ++nt)
        boff[nt] = (wn * 80 + nt * 16 + lr) * HDIM + quad * 8;

    float4 av[2][4];
    auto load_tile = [&](int ko) {
        const int k0 = ko * 64;
#pragma unroll
        for (int p = 0; p < 2; ++p) {
            long grow = (long)bm * 128 + arow0 + p * 64;
            if (grow < NATOMS) {
                const float4* src = (const float4*)(A + grow * HDIM + k0 + aseg);
                av[p][0] = src[0]; av[p][1] = src[1]; av[p][2] = src[2]; av[p][3] = src[3];
            } else {
                av[p][0] = av[p][1] = av[p][2] = av[p][3] = make_float4(0.f, 0.f, 0.f, 0.f);
            }
        }
    };
    auto cvt_store = [&](int buf) {
#pragma unroll
        for (int p = 0; p < 2; ++p) {
            int row = arow0 + p * 64;
            half8 h0 = {(_Float16)av[p][0].x, (_Float16)av[p][0].y, (_Float16)av[p][0].z, (_Float16)av[p][0].w,
                        (_Float16)av[p][1].x, (_Float16)av[p][1].y, (_Float16)av[p][1].z, (_Float16)av[p][1].w};
            half8 h1 = {(_Float16)av[p][2].x, (_Float16)av[p][2].y, (_Float16)av[p][2].z, (_Float16)av[p][2].w,
                        (_Float16)av[p][3].x, (_Float16)av[p][3].y, (_Float16)av[p][3].z, (_Float16)av[p][3].w};
            *(half8*)&As[buf][row][aseg]     = h0;
            *(half8*)&As[buf][row][aseg + 8] = h1;
        }
    };

    // ---- prologue: stage tile 0
    load_tile(0);
    cvt_store(0);          // vmcnt(0) wait happens here, once
    __syncthreads();

    for (int ko = 0; ko < 8; ++ko) {
        const int k0  = ko * 64;
        const int cur = ko & 1;

        // ---- issue B fragment loads FIRST (both kk batches), then the A
        // prefetch: consuming bf then needs only a partial vmcnt that leaves
        // the A loads in flight until cvt_store at the end of the iteration.
        half8 bfa[5], bfb[5];
#pragma unroll
        for (int nt = 0; nt < 5; ++nt) bfa[nt] = *(const half8*)(Bm + boff[nt] + k0);
#pragma unroll
        for (int nt = 0; nt < 5; ++nt) bfb[nt] = *(const half8*)(Bm + boff[nt] + k0 + 32);
        if (ko < 7) load_tile(ko + 1);

        // ---- MFMA on resident buffer
        {
            half8 af[4];
#pragma unroll
            for (int mt = 0; mt < 4; ++mt)
                af[mt] = *(const half8*)&As[cur][wm * 64 + mt * 16 + lr][quad * 8];
#pragma unroll
            for (int mt = 0; mt < 4; ++mt)
#pragma unroll
                for (int nt = 0; nt < 5; ++nt)
                    acc[mt][nt] = __builtin_amdgcn_mfma_f32_16x16x32_f16(af[mt], bfa[nt], acc[mt][nt], 0, 0, 0);
#pragma unroll
            for (int mt = 0; mt < 4; ++mt)
                af[mt] = *(const half8*)&As[cur][wm * 64 + mt * 16 + lr][32 + quad * 8];
#pragma unroll
            for (int mt = 0; mt < 4; ++mt)
#pragma unroll
                for (int nt = 0; nt < 5; ++nt)
                    acc[mt][nt] = __builtin_amdgcn_mfma_f32_16x16x32_f16(af[mt], bfb[nt], acc[mt][nt], 0, 0, 0);
        }

        // ---- fused segment-sum pooling over this tile's 64 columns
        // (batched LDS reads; register-only segment logic; same fp add order)
        {
            float psum = 0.f;
            int pg = bg[pq * 32];
#pragma unroll
            for (int rb = 0; rb < 32; rb += 8) {
                float vals[8];
#pragma unroll
                for (int i = 0; i < 8; ++i)
                    vals[i] = (float)As[cur][pq * 32 + rb + i][pc];
#pragma unroll
                for (int i = 0; i < 8; ++i) {
                    int r = pq * 32 + rb + i;
                    int gid = bg[r];                      // wave-uniform broadcast
                    if (gid != pg) {                      // wave-uniform branch
                        if (pg >= 0) atomicAdd(&GEf[(size_t)pg * HDIM + k0 + pc], psum);
                        psum = 0.f; pg = gid;
                    }
                    psum += vals[i];
                }
            }
            if (pg >= 0) atomicAdd(&GEf[(size_t)pg * HDIM + k0 + pc], psum);
        }

        // ---- land the prefetched tile into the other buffer
        if (ko < 7) {
            cvt_store(cur ^ 1);       // vmcnt(0) for the prefetch waits HERE
            __syncthreads();          // single barrier per ko
        }
    }

    // ---- epilogue: +bias, scatter to node_pred / P
    float biasv[5];
#pragma unroll
    for (int nt = 0; nt < 5; ++nt) biasv[nt] = bias[wn * 80 + nt * 16 + lr];
#pragma unroll
    for (int mt = 0; mt < 4; ++mt) {
        int rbase = bm * 128 + wm * 64 + mt * 16 + quad * 4;
#pragma unroll
        for (int r = 0; r < 4; ++r) {
            int grow = rbase + r;
            if (grow >= NATOMS) continue;
#pragma unroll
            for (int nt = 0; nt < 5; ++nt) {
                int gcol = wn * 80 + nt * 16 + lr;
                float v = acc[mt][nt][r] + biasv[nt];
                if (gcol < AF)                  node_out[(long)grow * AF + gcol] = v;
                else if (gcol < AF + BFEAT)     P[(long)grow * 16 + (gcol - AF)] = v;
            }
        }
    }
}

// ---------------------------------------------------------------------------
// Edge head: keep[k] = 2k (rev[e] = e^1 on pristine input), so
// edge_pred[k] = 0.5*(P[heads[2k]] + P[tails[2k]]). 64 bonds per block,
// 4 threads/bond, float4 gathers from P (rows are 64 B).
// ---------------------------------------------------------------------------
__global__ __launch_bounds__(256) void edge_kernel(const int* __restrict__ ei,
                                                   const float* __restrict__ P,
                                                   float* __restrict__ eout) {
    int t  = threadIdx.x;
    int q  = t & 3, bi = t >> 2;
    int b  = blockIdx.x * 64 + bi;
    if (b >= NBOND) return;
    int e  = 2 * b;
    int a1 = ei[e];
    int a2 = ei[NEDGE + e];
    const float4 v1 = *(const float4*)(P + (size_t)a1 * 16 + q * 4);
    const float4 v2 = *(const float4*)(P + (size_t)a2 * 16 + q * 4);
    float r[4] = {0.5f * (v1.x + v2.x), 0.5f * (v1.y + v2.y),
                  0.5f * (v1.z + v2.z), 0.5f * (v1.w + v2.w)};
    float* dst = eout + (size_t)b * BFEAT + q * 4;
    int rem = BFEAT - q * 4;      // 14,10,6,2 for q=0..3 -> q<3 full, q=3 two
#pragma unroll
    for (int i = 0; i < 4; ++i)
        if (i < rem) dst[i] = r[i];
}

// ---------------------------------------------------------------------------
// Graph head: relu(GE @ Wg1 + b_g1) @ Wg2 (+b_g2, pre-initialized). GEMM
// 4096x512x512; A staged from fp32 GEf with f16 cast, B from f16 Wg1t.
// Fused relu/dot epilogue; 16-lane shuffle reduce, atomicAdd per row.
// ---------------------------------------------------------------------------
__global__ __launch_bounds__(256) void gemm_graph(const float* __restrict__ GEf,
                                                  const _Float16* __restrict__ Bt,
                                                  const float* __restrict__ bg1,
                                                  const float* __restrict__ wg2,
                                                  float* __restrict__ gpred) {
    __shared__ _Float16 As[128][72];
    __shared__ _Float16 Bs[128][72];

    const int t   = threadIdx.x;
    const int bmb = blockIdx.x, bnb = blockIdx.y;
    const int w   = t >> 6, l = t & 63, quad = l >> 4, lr = l & 15;
    const int wm  = w & 1, wn = w >> 1;

    floatx4 acc[4][4];
    for (int mt = 0; mt < 4; ++mt)
        for (int nt = 0; nt < 4; ++nt)
            acc[mt][nt] = (floatx4){0.f, 0.f, 0.f, 0.f};

    const int arow0 = t >> 2;          // 0..63
    const int aseg  = (t & 3) * 16;

    for (int ko = 0; ko < 8; ++ko) {
        const int k0 = ko * 64;
        float4 av[2][4];
        for (int p = 0; p < 2; ++p) {
            int row = bmb * 128 + arow0 + p * 64;   // always < 4096
            const float4* src = (const float4*)(GEf + (size_t)row * HDIM + k0 + aseg);
            av[p][0] = src[0]; av[p][1] = src[1]; av[p][2] = src[2]; av[p][3] = src[3];
        }
        uint4 bvv[4];
        for (int it = 0; it < 4; ++it) {
            int idx = t + it * 256;            // < 1024
            int row = idx >> 3, c = (idx & 7) * 8;
            bvv[it] = *(const uint4*)(Bt + (size_t)(bnb * 128 + row) * HDIM + k0 + c);
        }
        __syncthreads();
        for (int p = 0; p < 2; ++p) {
            int row = arow0 + p * 64;
            half8 h0 = {(_Float16)av[p][0].x, (_Float16)av[p][0].y, (_Float16)av[p][0].z, (_Float16)av[p][0].w,
                        (_Float16)av[p][1].x, (_Float16)av[p][1].y, (_Float16)av[p][1].z, (_Float16)av[p][1].w};
            half8 h1 = {(_Float16)av[p][2].x, (_Float16)av[p][2].y, (_Float16)av[p][2].z, (_Float16)av[p][2].w,
                        (_Float16)av[p][3].x, (_Float16)av[p][3].y, (_Float16)av[p][3].z, (_Float16)av[p][3].w};
            *(half8*)&As[row][aseg]     = h0;
            *(half8*)&As[row][aseg + 8] = h1;
        }
        for (int it = 0; it < 4; ++it) {
            int idx = t + it * 256;
            int row = idx >> 3, c = (idx & 7) * 8;
            *(uint4*)&Bs[row][c] = bvv[it];
        }
        __syncthreads();
        for (int kk = 0; kk < 64; kk += 32) {
            half8 af[4], bf[4];
            for (int mt = 0; mt < 4; ++mt)
                af[mt] = *(const half8*)&As[wm * 64 + mt * 16 + lr][kk + quad * 8];
            for (int nt = 0; nt < 4; ++nt)
                bf[nt] = *(const half8*)&Bs[wn * 64 + nt * 16 + lr][kk + quad * 8];
            for (int mt = 0; mt < 4; ++mt)
                for (int nt = 0; nt < 4; ++nt)
                    acc[mt][nt] = __builtin_amdgcn_mfma_f32_16x16x32_f16(af[mt], bf[nt], acc[mt][nt], 0, 0, 0);
        }
    }

    float bg1v[4], wg2v[4];
    for (int nt = 0; nt < 4; ++nt) {
        int col = bnb * 128 + wn * 64 + nt * 16 + lr;
        bg1v[nt] = bg1[col];
        wg2v[nt] = wg2[col];
    }
    for (int mt = 0; mt < 4; ++mt) {
        for (int r = 0; r < 4; ++r) {
            int row = bmb * 128 + wm * 64 + mt * 16 + quad * 4 + r;
            float partial = 0.f;
            for (int nt = 0; nt < 4; ++nt) {
                float v = acc[mt][nt][r] + bg1v[nt];
                v = v > 0.f ? v : 0.f;
                partial += v * wg2v[nt];
            }
            partial += __shfl_xor(partial, 1);
            partial += __shfl_xor(partial, 2);
            partial += __shfl_xor(partial, 4);
            partial += __shfl_xor(partial, 8);
            if (lr == 0) atomicAdd(&gpred[row], partial);
        }
    }
}

// ---------------------------------------------------------------------------
extern "C" void kernel_launch(void* const* d_in, const int* in_sizes, int n_in,
                              void* d_out, int out_size, void* d_ws, size_t ws_size,
                              hipStream_t stream) {
    const float* A    = (const float*)d_in[0];
    const float* Wn   = (const float*)d_in[1];
    const float* bn   = (const float*)d_in[2];
    const float* We   = (const float*)d_in[3];
    const float* be   = (const float*)d_in[4];
    const float* Wg1  = (const float*)d_in[5];
    const float* bg1  = (const float*)d_in[6];
    const float* Wg2  = (const float*)d_in[7];
    const float* bg2  = (const float*)d_in[8];
    const int*   ei   = (const int*)d_in[9];
    const int*   batch= (const int*)d_in[11];

    char* ws = (char*)d_ws;
    float*    P    = (float*)(ws + WS_P);
    _Float16* Bmat = (_Float16*)(ws + WS_BMAT);
    float*    bias = (float*)(ws + WS_BIAS);
    float*    GEf  = (float*)(ws + WS_GEF);
    _Float16* Wg1t = (_Float16*)(ws + WS_WG1T);

    float* node_out = (float*)d_out;
    float* edge_out = node_out + NODE_OUT_SZ;
    float* gpred    = edge_out + EDGE_OUT_SZ;

    pack_kernel<<<dim3(1361), dim3(256), 0, stream>>>(Wn, bn, We, be, Wg1, bg2, Bmat, bias, Wg1t, gpred);
    zero_ge<<<dim3(NGRAPH * HDIM / 4 / 256), dim3(256), 0, stream>>>((float4*)GEf);
    gemm_node<<<dim3((NATOMS + 127) / 128), dim3(256), 0, stream>>>(A, Bmat, bias, batch, node_out, P, GEf);
    edge_kernel<<<dim3((NBOND + 63) / 64), dim3(256), 0, stream>>>(ei, P, edge_out);
    gemm_graph<<<dim3(32, 4), dim3(256), 0, stream>>>(GEf, Wg1t, bg1, Wg2, gpred);
}

// Round 2
// 762.873 us; speedup vs baseline: 1.0504x; 1.0504x over previous
//
#include <hip/hip_runtime.h>

// Problem constants (fixed by reference)
#define NATOMS 200000
#define NEDGE  800000
#define NBOND  400000   // NEDGE/2
#define HDIM   512
#define AF     133
#define BFEAT  14
#define NGRAPH 4096

// d_out layout: node_pred [NATOMS*AF] | edge_pred [NBOND*BFEAT] | graph_pred [NGRAPH]
#define NODE_OUT_SZ (NATOMS * AF)          // 26,600,000
#define EDGE_OUT_SZ (NBOND * BFEAT)        //  5,600,000

// ws layout (bytes)
#define WS_P     0                          // float  [NATOMS][16]  (cols 0..13 used)  12,800,000 B
#define WS_BMAT  12800000                   // f16    [160][512]    163,840 B  (n-major, transposed)
#define WS_BIAS  12963840                   // float  [160]         640 B
#define WS_GEF   12964480                   // float  [4096][512]   8,388,608 B (pooled emb, fp32, atomics)
#define WS_WG1T  21353088                   // f16    [512][512]    524,288 B (n-major)

typedef _Float16 half8 __attribute__((ext_vector_type(8)));
typedef float floatx4 __attribute__((ext_vector_type(4)));

// ---------------------------------------------------------------------------
// Pack: combined B matrix [W_node | W_edge] transposed to n-major f16, bias,
// W_g1 transposed f16, graph_pred init to b_g2.
// ---------------------------------------------------------------------------
__global__ void pack_kernel(const float* __restrict__ Wn, const float* __restrict__ bn,
                            const float* __restrict__ We, const float* __restrict__ be,
                            const float* __restrict__ Wg1, const float* __restrict__ bg2,
                            _Float16* __restrict__ Bmat, float* __restrict__ bias,
                            _Float16* __restrict__ Wg1t, float* __restrict__ gpred) {
    int idx = blockIdx.x * 256 + threadIdx.x;
    if (idx < 160 * 512) {                      // Bmat[n][k] = W[k][n]
        int n = idx >> 9, k = idx & 511;
        float v = 0.f;
        if (n < AF)              v = Wn[k * AF + n];
        else if (n < AF + BFEAT) v = We[k * BFEAT + (n - AF)];
        Bmat[idx] = (_Float16)v;
    } else if (idx < 160 * 512 + 512 * 512) {   // Wg1t[n][k] = Wg1[k][n]
        int i = idx - 160 * 512;
        int n = i >> 9, k = i & 511;
        Wg1t[i] = (_Float16)Wg1[k * HDIM + n];
    } else if (idx < 160 * 512 + 512 * 512 + 160) {
        int n = idx - (160 * 512 + 512 * 512);
        float v = 0.f;
        if (n < AF)              v = bn[n];
        else if (n < AF + BFEAT) v = be[n - AF];
        bias[n] = v;
    } else if (idx < 160 * 512 + 512 * 512 + 160 + NGRAPH) {
        gpred[idx - (160 * 512 + 512 * 512 + 160)] = bg2[0];
    }
}

// Zero the fp32 graph-embedding accumulator (ws is poisoned 0xAA).
__global__ void zero_ge(float4* __restrict__ GEf4) {
    GEf4[blockIdx.x * 256 + threadIdx.x] = make_float4(0.f, 0.f, 0.f, 0.f);
}

// ---------------------------------------------------------------------------
// GEMM1: C[N x 160] = A(f32->f16)[N x 512] @ Bmat^T, cols 0..132 -> node_pred,
// cols 133..146 -> P (stride 16). BM=128 BN=160 BK=64, 4 waves (2x2), wave
// tile 64x80 = 4x5 MFMA 16x16x32 f16 tiles.  (v1 loop structure: Bs staged,
// two barriers per ko — proven 260 us.)
//
// v3 changes vs v1:
//  - pooling LDS reads batched 8-wide (same fp add order; register segment
//    logic) to shorten the serial chain.
//  - COALESCED EPILOGUE: accumulators staged through LDS (union over As/Bs,
//    same 41,984 B) and written out as contiguous full rows. v1's scattered
//    64B chunks straddled the 532B rows -> partial-sector evictions ->
//    WRITE_SIZE 332 MB vs ~120 MB payload. This writes every sector fully,
//    temporally adjacent, wave-coalesced.
// FUSED POOLING: wave w sums rows w*32..w*32+31 of the resident tile for its
// 64 columns, segmented by graph id (wave-uniform branch), one coalesced
// 256B fp32 atomicAdd burst per graph boundary into GEf.
// ---------------------------------------------------------------------------
__global__ __launch_bounds__(256) void gemm_node(const float* __restrict__ A,
                                                 const _Float16* __restrict__ Bm,
                                                 const float* __restrict__ bias,
                                                 const int* __restrict__ batch,
                                                 float* __restrict__ node_out,
                                                 float* __restrict__ P,
                                                 float* __restrict__ GEf) {
    __shared__ union SMem {
        struct {
            _Float16 As[128][72];   // +8 pad: 2-way-max bank aliasing
            _Float16 Bs[160][72];
            int      bg[128];
        } m;                        // 41,984 B
        float C[64][164];           // 41,984 B epilogue staging (4-row bank shift 16)
    } sm;

    const int t    = threadIdx.x;
    const int bm   = blockIdx.x;
    const int w    = t >> 6, l = t & 63, quad = l >> 4, lr = l & 15;
    const int wm   = w & 1, wn = w >> 1;

    if (t < 128) {
        int grow = bm * 128 + t;
        sm.m.bg[t] = (grow < NATOMS) ? batch[grow] : -1;
    }

    floatx4 acc[4][5];
#pragma unroll
    for (int mt = 0; mt < 4; ++mt)
#pragma unroll
        for (int nt = 0; nt < 5; ++nt)
            acc[mt][nt] = (floatx4){0.f, 0.f, 0.f, 0.f};

    const int arow0 = t >> 2;          // 0..63
    const int aseg  = (t & 3) * 16;    // 0,16,32,48
    const int pc    = t & 63;          // pooling column within the ko tile
    const int pq    = w;               // pooling row-quarter = wave id

    for (int ko = 0; ko < 8; ++ko) {
        const int k0 = ko * 64;
        // ---- global loads into regs
        float4 av[2][4];
#pragma unroll
        for (int p = 0; p < 2; ++p) {
            int row = arow0 + p * 64;
            long grow = (long)bm * 128 + row;
            if (grow < NATOMS) {
                const float4* src = (const float4*)(A + grow * HDIM + k0 + aseg);
                av[p][0] = src[0]; av[p][1] = src[1]; av[p][2] = src[2]; av[p][3] = src[3];
            } else {
                av[p][0] = av[p][1] = av[p][2] = av[p][3] = make_float4(0.f, 0.f, 0.f, 0.f);
            }
        }
        uint4 bv[5];
#pragma unroll
        for (int it = 0; it < 5; ++it) {
            int idx = t + it * 256;            // < 1280
            int row = idx >> 3, c = (idx & 7) * 8;
            bv[it] = *(const uint4*)(Bm + row * HDIM + k0 + c);
        }
        __syncthreads();   // protect previous iteration's LDS reads (MFMA + pooling)
        // ---- LDS writes (fp32 -> f16 cast for A)
#pragma unroll
        for (int p = 0; p < 2; ++p) {
            int row = arow0 + p * 64;
            half8 h0 = {(_Float16)av[p][0].x, (_Float16)av[p][0].y, (_Float16)av[p][0].z, (_Float16)av[p][0].w,
                        (_Float16)av[p][1].x, (_Float16)av[p][1].y, (_Float16)av[p][1].z, (_Float16)av[p][1].w};
            half8 h1 = {(_Float16)av[p][2].x, (_Float16)av[p][2].y, (_Float16)av[p][2].z, (_Float16)av[p][2].w,
                        (_Float16)av[p][3].x, (_Float16)av[p][3].y, (_Float16)av[p][3].z, (_Float16)av[p][3].w};
            *(half8*)&sm.m.As[row][aseg]     = h0;
            *(half8*)&sm.m.As[row][aseg + 8] = h1;
        }
#pragma unroll
        for (int it = 0; it < 5; ++it) {
            int idx = t + it * 256;
            int row = idx >> 3, c = (idx & 7) * 8;
            *(uint4*)&sm.m.Bs[row][c] = bv[it];
        }
        __syncthreads();
        // ---- MFMA
#pragma unroll
        for (int kk = 0; kk < 64; kk += 32) {
            half8 af[4], bf[5];
#pragma unroll
            for (int mt = 0; mt < 4; ++mt)
                af[mt] = *(const half8*)&sm.m.As[wm * 64 + mt * 16 + lr][kk + quad * 8];
#pragma unroll
            for (int nt = 0; nt < 5; ++nt)
                bf[nt] = *(const half8*)&sm.m.Bs[wn * 80 + nt * 16 + lr][kk + quad * 8];
#pragma unroll
            for (int mt = 0; mt < 4; ++mt)
#pragma unroll
                for (int nt = 0; nt < 5; ++nt)
                    acc[mt][nt] = __builtin_amdgcn_mfma_f32_16x16x32_f16(af[mt], bf[nt], acc[mt][nt], 0, 0, 0);
        }
        // ---- fused segment-sum pooling over this tile's 64 columns
        // (batched LDS reads; register-only segment logic; same fp add order)
        {
            float psum = 0.f;
            int pg = sm.m.bg[pq * 32];
#pragma unroll
            for (int rb = 0; rb < 32; rb += 8) {
                float vals[8];
#pragma unroll
                for (int i = 0; i < 8; ++i)
                    vals[i] = (float)sm.m.As[pq * 32 + rb + i][pc];
#pragma unroll
                for (int i = 0; i < 8; ++i) {
                    int gid = sm.m.bg[pq * 32 + rb + i];  // wave-uniform broadcast
                    if (gid != pg) {                      // wave-uniform branch
                        if (pg >= 0) atomicAdd(&GEf[(size_t)pg * HDIM + k0 + pc], psum);
                        psum = 0.f; pg = gid;
                    }
                    psum += vals[i];
                }
            }
            if (pg >= 0) atomicAdd(&GEf[(size_t)pg * HDIM + k0 + pc], psum);
        }
    }

    // ---- epilogue: +bias, stage through LDS, coalesced contiguous writeback
    float biasv[5];
#pragma unroll
    for (int nt = 0; nt < 5; ++nt) biasv[nt] = bias[wn * 80 + nt * 16 + lr];

#pragma unroll
    for (int phase = 0; phase < 2; ++phase) {
        __syncthreads();   // previous LDS use (pooling / prev phase copy) done
        if (wm == phase) { // waves holding rows phase*64 .. phase*64+63
#pragma unroll
            for (int mt = 0; mt < 4; ++mt)
#pragma unroll
                for (int rr = 0; rr < 4; ++rr) {
                    int lrow = mt * 16 + quad * 4 + rr;          // 0..63
#pragma unroll
                    for (int nt = 0; nt < 5; ++nt)
                        sm.C[lrow][wn * 80 + nt * 16 + lr] = acc[mt][nt][rr] + biasv[nt];
                }
        }
        __syncthreads();
        const int gbase = bm * 128 + phase * 64;
        // node_pred: 64 contiguous rows of 133 floats -> one contiguous span,
        // lane-consecutive scalar stores (full sectors, wave-coalesced).
        for (int r16 = 0; r16 < 16; ++r16) {
            int row  = w * 16 + r16;          // 0..63
            int grow = gbase + row;
            if (grow < NATOMS) {
                for (int c = l; c < AF; c += 64)
                    node_out[(long)grow * AF + c] = sm.C[row][c];
            }
        }
        // P: full 16-float (64 B) rows, cols 14/15 are zero padding.
        for (int idx = t; idx < 1024; idx += 256) {
            int r = idx >> 4, c = idx & 15;
            int grow = gbase + r;
            if (grow < NATOMS) P[(size_t)grow * 16 + c] = sm.C[r][AF + c];
        }
    }
}

// ---------------------------------------------------------------------------
// Edge head: keep[k] = 2k (rev[e] = e^1 on pristine input), so
// edge_pred[k] = 0.5*(P[heads[2k]] + P[tails[2k]]). 64 bonds per block,
// 4 threads/bond, float4 gathers from P (rows are 64 B).
// ---------------------------------------------------------------------------
__global__ __launch_bounds__(256) void edge_kernel(const int* __restrict__ ei,
                                                   const float* __restrict__ P,
                                                   float* __restrict__ eout) {
    int t  = threadIdx.x;
    int q  = t & 3, bi = t >> 2;
    int b  = blockIdx.x * 64 + bi;
    if (b >= NBOND) return;
    int e  = 2 * b;
    int a1 = ei[e];
    int a2 = ei[NEDGE + e];
    const float4 v1 = *(const float4*)(P + (size_t)a1 * 16 + q * 4);
    const float4 v2 = *(const float4*)(P + (size_t)a2 * 16 + q * 4);
    float r[4] = {0.5f * (v1.x + v2.x), 0.5f * (v1.y + v2.y),
                  0.5f * (v1.z + v2.z), 0.5f * (v1.w + v2.w)};
    float* dst = eout + (size_t)b * BFEAT + q * 4;
    int rem = BFEAT - q * 4;      // 14,10,6,2 for q=0..3
#pragma unroll
    for (int i = 0; i < 4; ++i)
        if (i < rem) dst[i] = r[i];
}

// ---------------------------------------------------------------------------
// Graph head: relu(GE @ Wg1 + b_g1) @ Wg2 (+b_g2, pre-initialized). GEMM
// 4096x512x512; A staged from fp32 GEf with f16 cast, B from f16 Wg1t.
// Fused relu/dot epilogue; 16-lane shuffle reduce, atomicAdd per row.
// ---------------------------------------------------------------------------
__global__ __launch_bounds__(256) void gemm_graph(const float* __restrict__ GEf,
                                                  const _Float16* __restrict__ Bt,
                                                  const float* __restrict__ bg1,
                                                  const float* __restrict__ wg2,
                                                  float* __restrict__ gpred) {
    __shared__ _Float16 As[128][72];
    __shared__ _Float16 Bs[128][72];

    const int t   = threadIdx.x;
    const int bmb = blockIdx.x, bnb = blockIdx.y;
    const int w   = t >> 6, l = t & 63, quad = l >> 4, lr = l & 15;
    const int wm  = w & 1, wn = w >> 1;

    floatx4 acc[4][4];
    for (int mt = 0; mt < 4; ++mt)
        for (int nt = 0; nt < 4; ++nt)
            acc[mt][nt] = (floatx4){0.f, 0.f, 0.f, 0.f};

    const int arow0 = t >> 2;          // 0..63
    const int aseg  = (t & 3) * 16;

    for (int ko = 0; ko < 8; ++ko) {
        const int k0 = ko * 64;
        float4 av[2][4];
        for (int p = 0; p < 2; ++p) {
            int row = bmb * 128 + arow0 + p * 64;   // always < 4096
            const float4* src = (const float4*)(GEf + (size_t)row * HDIM + k0 + aseg);
            av[p][0] = src[0]; av[p][1] = src[1]; av[p][2] = src[2]; av[p][3] = src[3];
        }
        uint4 bvv[4];
        for (int it = 0; it < 4; ++it) {
            int idx = t + it * 256;            // < 1024
            int row = idx >> 3, c = (idx & 7) * 8;
            bvv[it] = *(const uint4*)(Bt + (size_t)(bnb * 128 + row) * HDIM + k0 + c);
        }
        __syncthreads();
        for (int p = 0; p < 2; ++p) {
            int row = arow0 + p * 64;
            half8 h0 = {(_Float16)av[p][0].x, (_Float16)av[p][0].y, (_Float16)av[p][0].z, (_Float16)av[p][0].w,
                        (_Float16)av[p][1].x, (_Float16)av[p][1].y, (_Float16)av[p][1].z, (_Float16)av[p][1].w};
            half8 h1 = {(_Float16)av[p][2].x, (_Float16)av[p][2].y, (_Float16)av[p][2].z, (_Float16)av[p][2].w,
                        (_Float16)av[p][3].x, (_Float16)av[p][3].y, (_Float16)av[p][3].z, (_Float16)av[p][3].w};
            *(half8*)&As[row][aseg]     = h0;
            *(half8*)&As[row][aseg + 8] = h1;
        }
        for (int it = 0; it < 4; ++it) {
            int idx = t + it * 256;
            int row = idx >> 3, c = (idx & 7) * 8;
            *(uint4*)&Bs[row][c] = bvv[it];
        }
        __syncthreads();
        for (int kk = 0; kk < 64; kk += 32) {
            half8 af[4], bf[4];
            for (int mt = 0; mt < 4; ++mt)
                af[mt] = *(const half8*)&As[wm * 64 + mt * 16 + lr][kk + quad * 8];
            for (int nt = 0; nt < 4; ++nt)
                bf[nt] = *(const half8*)&Bs[wn * 64 + nt * 16 + lr][kk + quad * 8];
            for (int mt = 0; mt < 4; ++mt)
                for (int nt = 0; nt < 4; ++nt)
                    acc[mt][nt] = __builtin_amdgcn_mfma_f32_16x16x32_f16(af[mt], bf[nt], acc[mt][nt], 0, 0, 0);
        }
    }

    float bg1v[4], wg2v[4];
    for (int nt = 0; nt < 4; ++nt) {
        int col = bnb * 128 + wn * 64 + nt * 16 + lr;
        bg1v[nt] = bg1[col];
        wg2v[nt] = wg2[col];
    }
    for (int mt = 0; mt < 4; ++mt) {
        for (int r = 0; r < 4; ++r) {
            int row = bmb * 128 + wm * 64 + mt * 16 + quad * 4 + r;
            float partial = 0.f;
            for (int nt = 0; nt < 4; ++nt) {
                float v = acc[mt][nt][r] + bg1v[nt];
                v = v > 0.f ? v : 0.f;
                partial += v * wg2v[nt];
            }
            partial += __shfl_xor(partial, 1);
            partial += __shfl_xor(partial, 2);
            partial += __shfl_xor(partial, 4);
            partial += __shfl_xor(partial, 8);
            if (lr == 0) atomicAdd(&gpred[row], partial);
        }
    }
}

// ---------------------------------------------------------------------------
extern "C" void kernel_launch(void* const* d_in, const int* in_sizes, int n_in,
                              void* d_out, int out_size, void* d_ws, size_t ws_size,
                              hipStream_t stream) {
    const float* A    = (const float*)d_in[0];
    const float* Wn   = (const float*)d_in[1];
    const float* bn   = (const float*)d_in[2];
    const float* We   = (const float*)d_in[3];
    const float* be   = (const float*)d_in[4];
    const float* Wg1  = (const float*)d_in[5];
    const float* bg1  = (const float*)d_in[6];
    const float* Wg2  = (const float*)d_in[7];
    const float* bg2  = (const float*)d_in[8];
    const int*   ei   = (const int*)d_in[9];
    const int*   batch= (const int*)d_in[11];

    char* ws = (char*)d_ws;
    float*    P    = (float*)(ws + WS_P);
    _Float16* Bmat = (_Float16*)(ws + WS_BMAT);
    float*    bias = (float*)(ws + WS_BIAS);
    float*    GEf  = (float*)(ws + WS_GEF);
    _Float16* Wg1t = (_Float16*)(ws + WS_WG1T);

    float* node_out = (float*)d_out;
    float* edge_out = node_out + NODE_OUT_SZ;
    float* gpred    = edge_out + EDGE_OUT_SZ;

    pack_kernel<<<dim3(1361), dim3(256), 0, stream>>>(Wn, bn, We, be, Wg1, bg2, Bmat, bias, Wg1t, gpred);
    zero_ge<<<dim3(NGRAPH * HDIM / 4 / 256), dim3(256), 0, stream>>>((float4*)GEf);
    gemm_node<<<dim3((NATOMS + 127) / 128), dim3(256), 0, stream>>>(A, Bmat, bias, batch, node_out, P, GEf);
    edge_kernel<<<dim3((NBOND + 63) / 64), dim3(256), 0, stream>>>(ei, P, edge_out);
    gemm_graph<<<dim3(32, 4), dim3(256), 0, stream>>>(GEf, Wg1t, bg1, Wg2, gpred);
}

// Round 3
// 740.630 us; speedup vs baseline: 1.0819x; 1.0300x over previous
//
#include <hip/hip_runtime.h>

// Problem constants (fixed by reference)
#define NATOMS 200000
#define NEDGE  800000
#define NBOND  400000   // NEDGE/2
#define HDIM   512
#define AF     133
#define BFEAT  14
#define NGRAPH 4096

// d_out layout: node_pred [NATOMS*AF] | edge_pred [NBOND*BFEAT] | graph_pred [NGRAPH]
#define NODE_OUT_SZ (NATOMS * AF)          // 26,600,000
#define EDGE_OUT_SZ (NBOND * BFEAT)        //  5,600,000

// ws layout (bytes)
#define WS_P     0                          // float  [NATOMS][16]  (cols 0..13 used)  12,800,000 B
#define WS_BMAT  12800000                   // f16    [160][512]    163,840 B  (n-major, transposed)
#define WS_BIAS  12963840                   // float  [160]         640 B
#define WS_GEF   12964480                   // float  [4096][512]   8,388,608 B (pooled emb, fp32, atomics)
#define WS_WG1T  21353088                   // f16    [512][512]    524,288 B (n-major)

typedef _Float16 half8 __attribute__((ext_vector_type(8)));
typedef float floatx4 __attribute__((ext_vector_type(4)));

// ---------------------------------------------------------------------------
// Pack (v4): LDS-tiled transposes, coalesced both sides.
//  blocks 0..63   : Wg1t[n][k] = Wg1[k][n], 8x8 tiles of 64x64
//  blocks 64..87  : Bmat[n][k] = [Wn|We][k][n], 3 n-tiles x 8 k-tiles
//  block  88      : bias[160], gpred init to b_g2
// (old version did stride-532B/2KB scalar gathers -> fully uncoalesced)
// ---------------------------------------------------------------------------
__global__ __launch_bounds__(256) void pack_kernel(
        const float* __restrict__ Wn, const float* __restrict__ bn,
        const float* __restrict__ We, const float* __restrict__ be,
        const float* __restrict__ Wg1, const float* __restrict__ bg2,
        _Float16* __restrict__ Bmat, float* __restrict__ bias,
        _Float16* __restrict__ Wg1t, float* __restrict__ gpred) {
    __shared__ float tile[64][65];
    const int b = blockIdx.x, t = threadIdx.x;
    const int c = t & 63, r0 = t >> 6;     // lane col, wave row-phase

    if (b < 64) {                          // Wg1 transpose
        int bi = b & 7, bj = b >> 3;       // bi: n-tile, bj: k-tile
        for (int r = r0; r < 64; r += 4)   // read Wg1[k][n], lane-consecutive n
            tile[r][c] = Wg1[(size_t)(bj * 64 + r) * HDIM + bi * 64 + c];
        __syncthreads();
        for (int r = r0; r < 64; r += 4)   // write Wg1t[n][k], lane-consecutive k
            Wg1t[(size_t)(bi * 64 + r) * HDIM + bj * 64 + c] = (_Float16)tile[c][r];
    } else if (b < 88) {                   // Bmat transpose ([Wn|We] columns)
        int bb = b - 64;
        int bi = bb % 3, bj = bb / 3;      // bi: n-tile (0..2), bj: k-tile
        for (int r = r0; r < 64; r += 4) {
            int k = bj * 64 + r, n = bi * 64 + c;
            float v = 0.f;
            if (n < AF)              v = Wn[(size_t)k * AF + n];
            else if (n < AF + BFEAT) v = We[(size_t)k * BFEAT + (n - AF)];
            tile[r][c] = v;
        }
        __syncthreads();
        for (int r = r0; r < 64; r += 4) {
            int n = bi * 64 + r;
            if (n < 160) Bmat[(size_t)n * HDIM + bj * 64 + c] = (_Float16)tile[c][r];
        }
    } else {                               // bias + gpred init
        for (int i = t; i < 160; i += 256) {
            float v = 0.f;
            if (i < AF)              v = bn[i];
            else                     v = be[i - AF];
            bias[i] = v;
        }
        float g = bg2[0];
        for (int i = t; i < NGRAPH; i += 256) gpred[i] = g;
    }
}

// Zero the fp32 graph-embedding accumulator (ws is poisoned 0xAA).
__global__ void zero_ge(float4* __restrict__ GEf4) {
    GEf4[blockIdx.x * 256 + threadIdx.x] = make_float4(0.f, 0.f, 0.f, 0.f);
}

// ---------------------------------------------------------------------------
// GEMM1: C[N x 160] = A(f32->f16)[N x 512] @ Bmat^T, cols 0..132 -> node_pred,
// cols 133..146 -> P (stride 16). BM=128 BN=160 BK=64, 4 waves (2x2), wave
// tile 64x80 = 4x5 MFMA 16x16x32 f16 tiles.
//
// v4: v1's LDS layout + traffic (As/Bs single-buffered, 41,984 B -> 3
// blocks/CU) with a register-prefetch pipeline (the part of v2 that worked):
// av/bv tiles for ko+1 are issued right after this ko's Bs write and land
// during MFMA+pooling. Per-iter order:
//   alpha-barrier -> write Bs(ko) [regs long since landed]
//   -> issue av(ko+1), bv(ko+1)
//   -> beta-barrier -> MFMA(ko) -> pooling(ko)
//   -> gamma-barrier -> cvt+store As(ko+1)  [vmcnt wait HERE, after ~600cyc]
// No vmcnt(0)-drain-with-zero-overlap anywhere (v1's structural stall).
// v1 pooling loop verbatim (v3's 8-wide batch caused 26.5M bank conflicts).
// v1 scattered epilogue verbatim (v3 proved WRITE_SIZE is atomics, not stores).
// ---------------------------------------------------------------------------
__global__ __launch_bounds__(256) void gemm_node(const float* __restrict__ A,
                                                 const _Float16* __restrict__ Bm,
                                                 const float* __restrict__ bias,
                                                 const int* __restrict__ batch,
                                                 float* __restrict__ node_out,
                                                 float* __restrict__ P,
                                                 float* __restrict__ GEf) {
    __shared__ _Float16 As[128][72];   // +8 pad: 2-way-max bank aliasing
    __shared__ _Float16 Bs[160][72];
    __shared__ int bg[128];

    const int t    = threadIdx.x;
    const int bm   = blockIdx.x;
    const int w    = t >> 6, l = t & 63, quad = l >> 4, lr = l & 15;
    const int wm   = w & 1, wn = w >> 1;

    if (t < 128) {
        int grow = bm * 128 + t;
        bg[t] = (grow < NATOMS) ? batch[grow] : -1;
    }

    floatx4 acc[4][5];
#pragma unroll
    for (int mt = 0; mt < 4; ++mt)
#pragma unroll
        for (int nt = 0; nt < 5; ++nt)
            acc[mt][nt] = (floatx4){0.f, 0.f, 0.f, 0.f};

    const int arow0 = t >> 2;          // 0..63
    const int aseg  = (t & 3) * 16;    // 0,16,32,48 (floats)
    const int pc    = t & 63;          // pooling column within the ko tile
    const int pq    = w;               // pooling row-quarter = wave id

    float4 av[2][4];                   // A prefetch regs (tile ko+1)
    uint4  bv[5];                      // B prefetch regs (tile ko+1)

    // ---- prologue: load tile 0, stage As(0); bv(0) stays in regs for iter 0
#pragma unroll
    for (int p = 0; p < 2; ++p) {
        long grow = (long)bm * 128 + arow0 + p * 64;
        if (grow < NATOMS) {
            const float4* src = (const float4*)(A + grow * HDIM + aseg);
            av[p][0] = src[0]; av[p][1] = src[1]; av[p][2] = src[2]; av[p][3] = src[3];
        } else {
            av[p][0] = av[p][1] = av[p][2] = av[p][3] = make_float4(0.f, 0.f, 0.f, 0.f);
        }
    }
#pragma unroll
    for (int it = 0; it < 5; ++it) {
        int idx = t + it * 256;            // < 1280
        int row = idx >> 3, c = (idx & 7) * 8;
        bv[it] = *(const uint4*)(Bm + row * HDIM + c);
    }
#pragma unroll
    for (int p = 0; p < 2; ++p) {          // cvt+store As(0): waits av only
        int row = arow0 + p * 64;
        half8 h0 = {(_Float16)av[p][0].x, (_Float16)av[p][0].y, (_Float16)av[p][0].z, (_Float16)av[p][0].w,
                    (_Float16)av[p][1].x, (_Float16)av[p][1].y, (_Float16)av[p][1].z, (_Float16)av[p][1].w};
        half8 h1 = {(_Float16)av[p][2].x, (_Float16)av[p][2].y, (_Float16)av[p][2].z, (_Float16)av[p][2].w,
                    (_Float16)av[p][3].x, (_Float16)av[p][3].y, (_Float16)av[p][3].z, (_Float16)av[p][3].w};
        *(half8*)&As[row][aseg]     = h0;
        *(half8*)&As[row][aseg + 8] = h1;
    }

    for (int ko = 0; ko < 8; ++ko) {
        const int k0 = ko * 64;

        __syncthreads();   // alpha: prev MFMA done reading Bs; As(ko) visible
        // ---- write Bs(ko) from regs loaded last iteration (long landed)
#pragma unroll
        for (int it = 0; it < 5; ++it) {
            int idx = t + it * 256;
            int row = idx >> 3, c = (idx & 7) * 8;
            *(uint4*)&Bs[row][c] = bv[it];
        }
        // ---- issue next tile's loads; they fly across MFMA+pooling
        if (ko < 7) {
            const int k1 = k0 + 64;
#pragma unroll
            for (int p = 0; p < 2; ++p) {
                long grow = (long)bm * 128 + arow0 + p * 64;
                if (grow < NATOMS) {
                    const float4* src = (const float4*)(A + grow * HDIM + k1 + aseg);
                    av[p][0] = src[0]; av[p][1] = src[1]; av[p][2] = src[2]; av[p][3] = src[3];
                } else {
                    av[p][0] = av[p][1] = av[p][2] = av[p][3] = make_float4(0.f, 0.f, 0.f, 0.f);
                }
            }
#pragma unroll
            for (int it = 0; it < 5; ++it) {
                int idx = t + it * 256;
                int row = idx >> 3, c = (idx & 7) * 8;
                bv[it] = *(const uint4*)(Bm + row * HDIM + k1 + c);
            }
        }
        __syncthreads();   // beta: Bs(ko) visible
        // ---- MFMA
#pragma unroll
        for (int kk = 0; kk < 64; kk += 32) {
            half8 af[4], bf[5];
#pragma unroll
            for (int mt = 0; mt < 4; ++mt)
                af[mt] = *(const half8*)&As[wm * 64 + mt * 16 + lr][kk + quad * 8];
#pragma unroll
            for (int nt = 0; nt < 5; ++nt)
                bf[nt] = *(const half8*)&Bs[wn * 80 + nt * 16 + lr][kk + quad * 8];
#pragma unroll
            for (int mt = 0; mt < 4; ++mt)
#pragma unroll
                for (int nt = 0; nt < 5; ++nt)
                    acc[mt][nt] = __builtin_amdgcn_mfma_f32_16x16x32_f16(af[mt], bf[nt], acc[mt][nt], 0, 0, 0);
        }
        // ---- fused segment-sum pooling (v1 loop verbatim)
        {
            float psum = 0.f;
            int pg = bg[pq * 32];
            for (int r = pq * 32; r < pq * 32 + 32; ++r) {
                int gid = bg[r];                      // wave-uniform broadcast
                if (gid != pg) {                      // wave-uniform branch
                    if (pg >= 0) atomicAdd(&GEf[(size_t)pg * HDIM + k0 + pc], psum);
                    psum = 0.f; pg = gid;
                }
                psum += (float)As[r][pc];
            }
            if (pg >= 0) atomicAdd(&GEf[(size_t)pg * HDIM + k0 + pc], psum);
        }
        // ---- land the prefetched A tile into As (vmcnt wait here, late)
        if (ko < 7) {
            __syncthreads();   // gamma: all waves done reading As(ko)
#pragma unroll
            for (int p = 0; p < 2; ++p) {
                int row = arow0 + p * 64;
                half8 h0 = {(_Float16)av[p][0].x, (_Float16)av[p][0].y, (_Float16)av[p][0].z, (_Float16)av[p][0].w,
                            (_Float16)av[p][1].x, (_Float16)av[p][1].y, (_Float16)av[p][1].z, (_Float16)av[p][1].w};
                half8 h1 = {(_Float16)av[p][2].x, (_Float16)av[p][2].y, (_Float16)av[p][2].z, (_Float16)av[p][2].w,
                            (_Float16)av[p][3].x, (_Float16)av[p][3].y, (_Float16)av[p][3].z, (_Float16)av[p][3].w};
                *(half8*)&As[row][aseg]     = h0;
                *(half8*)&As[row][aseg + 8] = h1;
            }
        }
    }

    // ---- epilogue: +bias, scatter to node_pred / P (v1 verbatim)
    float biasv[5];
#pragma unroll
    for (int nt = 0; nt < 5; ++nt) biasv[nt] = bias[wn * 80 + nt * 16 + lr];
#pragma unroll
    for (int mt = 0; mt < 4; ++mt) {
        int rbase = bm * 128 + wm * 64 + mt * 16 + quad * 4;
#pragma unroll
        for (int r = 0; r < 4; ++r) {
            int grow = rbase + r;
            if (grow >= NATOMS) continue;
#pragma unroll
            for (int nt = 0; nt < 5; ++nt) {
                int gcol = wn * 80 + nt * 16 + lr;
                float v = acc[mt][nt][r] + biasv[nt];
                if (gcol < AF)                  node_out[(long)grow * AF + gcol] = v;
                else if (gcol < AF + BFEAT)     P[(long)grow * 16 + (gcol - AF)] = v;
            }
        }
    }
}

// ---------------------------------------------------------------------------
// Edge head: keep[k] = 2k (rev[e] = e^1 on pristine input), so
// edge_pred[k] = 0.5*(P[heads[2k]] + P[tails[2k]]). 64 bonds per block,
// 4 threads/bond, float4 gathers from P (rows are 64 B).
// ---------------------------------------------------------------------------
__global__ __launch_bounds__(256) void edge_kernel(const int* __restrict__ ei,
                                                   const float* __restrict__ P,
                                                   float* __restrict__ eout) {
    int t  = threadIdx.x;
    int q  = t & 3, bi = t >> 2;
    int b  = blockIdx.x * 64 + bi;
    if (b >= NBOND) return;
    int e  = 2 * b;
    int a1 = ei[e];
    int a2 = ei[NEDGE + e];
    const float4 v1 = *(const float4*)(P + (size_t)a1 * 16 + q * 4);
    const float4 v2 = *(const float4*)(P + (size_t)a2 * 16 + q * 4);
    float r[4] = {0.5f * (v1.x + v2.x), 0.5f * (v1.y + v2.y),
                  0.5f * (v1.z + v2.z), 0.5f * (v1.w + v2.w)};
    float* dst = eout + (size_t)b * BFEAT + q * 4;
    int rem = BFEAT - q * 4;      // 14,10,6,2 for q=0..3
#pragma unroll
    for (int i = 0; i < 4; ++i)
        if (i < rem) dst[i] = r[i];
}

// ---------------------------------------------------------------------------
// Graph head: relu(GE @ Wg1 + b_g1) @ Wg2 (+b_g2, pre-initialized). GEMM
// 4096x512x512; A staged from fp32 GEf with f16 cast, B from f16 Wg1t.
// Fused relu/dot epilogue; 16-lane shuffle reduce, atomicAdd per row.
// ---------------------------------------------------------------------------
__global__ __launch_bounds__(256) void gemm_graph(const float* __restrict__ GEf,
                                                  const _Float16* __restrict__ Bt,
                                                  const float* __restrict__ bg1,
                                                  const float* __restrict__ wg2,
                                                  float* __restrict__ gpred) {
    __shared__ _Float16 As[128][72];
    __shared__ _Float16 Bs[128][72];

    const int t   = threadIdx.x;
    const int bmb = blockIdx.x, bnb = blockIdx.y;
    const int w   = t >> 6, l = t & 63, quad = l >> 4, lr = l & 15;
    const int wm  = w & 1, wn = w >> 1;

    floatx4 acc[4][4];
    for (int mt = 0; mt < 4; ++mt)
        for (int nt = 0; nt < 4; ++nt)
            acc[mt][nt] = (floatx4){0.f, 0.f, 0.f, 0.f};

    const int arow0 = t >> 2;          // 0..63
    const int aseg  = (t & 3) * 16;

    for (int ko = 0; ko < 8; ++ko) {
        const int k0 = ko * 64;
        float4 av[2][4];
        for (int p = 0; p < 2; ++p) {
            int row = bmb * 128 + arow0 + p * 64;   // always < 4096
            const float4* src = (const float4*)(GEf + (size_t)row * HDIM + k0 + aseg);
            av[p][0] = src[0]; av[p][1] = src[1]; av[p][2] = src[2]; av[p][3] = src[3];
        }
        uint4 bvv[4];
        for (int it = 0; it < 4; ++it) {
            int idx = t + it * 256;            // < 1024
            int row = idx >> 3, c = (idx & 7) * 8;
            bvv[it] = *(const uint4*)(Bt + (size_t)(bnb * 128 + row) * HDIM + k0 + c);
        }
        __syncthreads();
        for (int p = 0; p < 2; ++p) {
            int row = arow0 + p * 64;
            half8 h0 = {(_Float16)av[p][0].x, (_Float16)av[p][0].y, (_Float16)av[p][0].z, (_Float16)av[p][0].w,
                        (_Float16)av[p][1].x, (_Float16)av[p][1].y, (_Float16)av[p][1].z, (_Float16)av[p][1].w};
            half8 h1 = {(_Float16)av[p][2].x, (_Float16)av[p][2].y, (_Float16)av[p][2].z, (_Float16)av[p][2].w,
                        (_Float16)av[p][3].x, (_Float16)av[p][3].y, (_Float16)av[p][3].z, (_Float16)av[p][3].w};
            *(half8*)&As[row][aseg]     = h0;
            *(half8*)&As[row][aseg + 8] = h1;
        }
        for (int it = 0; it < 4; ++it) {
            int idx = t + it * 256;
            int row = idx >> 3, c = (idx & 7) * 8;
            *(uint4*)&Bs[row][c] = bvv[it];
        }
        __syncthreads();
        for (int kk = 0; kk < 64; kk += 32) {
            half8 af[4], bf[4];
            for (int mt = 0; mt < 4; ++mt)
                af[mt] = *(const half8*)&As[wm * 64 + mt * 16 + lr][kk + quad * 8];
            for (int nt = 0; nt < 4; ++nt)
                bf[nt] = *(const half8*)&Bs[wn * 64 + nt * 16 + lr][kk + quad * 8];
            for (int mt = 0; mt < 4; ++mt)
                for (int nt = 0; nt < 4; ++nt)
                    acc[mt][nt] = __builtin_amdgcn_mfma_f32_16x16x32_f16(af[mt], bf[nt], acc[mt][nt], 0, 0, 0);
        }
    }

    float bg1v[4], wg2v[4];
    for (int nt = 0; nt < 4; ++nt) {
        int col = bnb * 128 + wn * 64 + nt * 16 + lr;
        bg1v[nt] = bg1[col];
        wg2v[nt] = wg2[col];
    }
    for (int mt = 0; mt < 4; ++mt) {
        for (int r = 0; r < 4; ++r) {
            int row = bmb * 128 + wm * 64 + mt * 16 + quad * 4 + r;
            float partial = 0.f;
            for (int nt = 0; nt < 4; ++nt) {
                float v = acc[mt][nt][r] + bg1v[nt];
                v = v > 0.f ? v : 0.f;
                partial += v * wg2v[nt];
            }
            partial += __shfl_xor(partial, 1);
            partial += __shfl_xor(partial, 2);
            partial += __shfl_xor(partial, 4);
            partial += __shfl_xor(partial, 8);
            if (lr == 0) atomicAdd(&gpred[row], partial);
        }
    }
}

// ---------------------------------------------------------------------------
extern "C" void kernel_launch(void* const* d_in, const int* in_sizes, int n_in,
                              void* d_out, int out_size, void* d_ws, size_t ws_size,
                              hipStream_t stream) {
    const float* A    = (const float*)d_in[0];
    const float* Wn   = (const float*)d_in[1];
    const float* bn   = (const float*)d_in[2];
    const float* We   = (const float*)d_in[3];
    const float* be   = (const float*)d_in[4];
    const float* Wg1  = (const float*)d_in[5];
    const float* bg1  = (const float*)d_in[6];
    const float* Wg2  = (const float*)d_in[7];
    const float* bg2  = (const float*)d_in[8];
    const int*   ei   = (const int*)d_in[9];
    const int*   batch= (const int*)d_in[11];

    char* ws = (char*)d_ws;
    float*    P    = (float*)(ws + WS_P);
    _Float16* Bmat = (_Float16*)(ws + WS_BMAT);
    float*    bias = (float*)(ws + WS_BIAS);
    float*    GEf  = (float*)(ws + WS_GEF);
    _Float16* Wg1t = (_Float16*)(ws + WS_WG1T);

    float* node_out = (float*)d_out;
    float* edge_out = node_out + NODE_OUT_SZ;
    float* gpred    = edge_out + EDGE_OUT_SZ;

    pack_kernel<<<dim3(89), dim3(256), 0, stream>>>(Wn, bn, We, be, Wg1, bg2, Bmat, bias, Wg1t, gpred);
    zero_ge<<<dim3(NGRAPH * HDIM / 4 / 256), dim3(256), 0, stream>>>((float4*)GEf);
    gemm_node<<<dim3((NATOMS + 127) / 128), dim3(256), 0, stream>>>(A, Bmat, bias, batch, node_out, P, GEf);
    edge_kernel<<<dim3((NBOND + 63) / 64), dim3(256), 0, stream>>>(ei, P, edge_out);
    gemm_graph<<<dim3(32, 4), dim3(256), 0, stream>>>(GEf, Wg1t, bg1, Wg2, gpred);
}